// Round 6
// baseline (324.798 us; speedup 1.0000x reference)
//
#include <hip/hip_runtime.h>

typedef short short8 __attribute__((ext_vector_type(8)));
typedef short short4v __attribute__((ext_vector_type(4)));
typedef float f32x4 __attribute__((ext_vector_type(4)));

#define NT 550
#define NS 2209
#define NP 12
#define NBK 69
#define NSTILE 18
#define NGRP 9
#define GBK 8
#define GNRM 3.9894228040143f

typedef unsigned short bfu;

__device__ __forceinline__ bfu f2bf(float f) {
    unsigned int u = __float_as_uint(f);
    unsigned int r = (u + 0x7fffu + ((u >> 16) & 1u)) >> 16;
    return (bfu)r;
}

__device__ __forceinline__ float sigm(float x) {
    return __builtin_amdgcn_rcpf(1.0f + __expf(-x));
}

// ---------- weight conversion: fp32 -> transposed bf16 ----------
__global__ void k_prep(const float* __restrict__ W2, const float* __restrict__ W3,
                       const float* __restrict__ W4,
                       bfu* __restrict__ w2h, bfu* __restrict__ w3h, bfu* __restrict__ w4h) {
    int id = blockIdx.x * 256 + threadIdx.x;
    if (id < 8192) {                       // w2h[c][k]  c<128,k<64   from W2(64,128)
        int c = id >> 6, k = id & 63;
        w2h[id] = f2bf(W2[k * 128 + c]);
    } else if (id < 8192 + 32768) {        // w3h[c][k]  c<256,k<128  from W3(128,256)
        int j = id - 8192;
        int c = j >> 7, k = j & 127;
        w3h[j] = f2bf(W3[k * 256 + c]);
    } else {                               // w4h[s][k]  s<2304,k<256 from W4(256,2209)
        int j = id - 40960;
        int s = j >> 8, k = j & 255;
        w4h[j] = f2bf(s < NS ? W4[k * NS + s] : 0.0f);
    }
}

// ---------- bucketing ----------
__global__ void k_count(const float* __restrict__ el, int* __restrict__ counts) {
    int id = blockIdx.x * 256 + threadIdx.x;
    float z = el[id * 3 + 2];
    int bk = (int)(z * 0.125f);
    bk = bk < 0 ? 0 : (bk > NBK - 1 ? NBK - 1 : bk);
    atomicAdd(&counts[(id >> 13) * NBK + bk], 1);
}

__global__ void k_scan(const int* __restrict__ counts, int* __restrict__ offs) {
    __shared__ int a[512];
    int tid = threadIdx.x;
    int v = (tid < 4 * NBK) ? counts[tid] : 0;
    a[tid] = v;
    __syncthreads();
    for (int s = 1; s < 512; s <<= 1) {
        int t = (tid >= s) ? a[tid - s] : 0;
        __syncthreads();
        a[tid] += t;
        __syncthreads();
    }
    if (tid < 4 * NBK) offs[tid] = a[tid] - v;
}

__global__ void k_scatter(const float* __restrict__ el, const int* __restrict__ offs,
                          int* __restrict__ cur, int* __restrict__ idxl) {
    int id = blockIdx.x * 256 + threadIdx.x;
    float z = el[id * 3 + 2];
    int bk = (int)(z * 0.125f);
    bk = bk < 0 ? 0 : (bk > NBK - 1 ? NBK - 1 : bk);
    int key = (id >> 13) * NBK + bk;
    int pos = offs[key] + atomicAdd(&cur[key], 1);
    idxl[pos] = id;
}

// ---------- phase A: sipm MLP layers 1-3 -> s3h (linear, bf16) ----------
__global__ __launch_bounds__(256, 1) void k_mlp(
    const float* __restrict__ el,
    const float* __restrict__ Ws1, const float* __restrict__ bs1,
    const float* __restrict__ bs2, const float* __restrict__ bs3,
    const bfu* __restrict__ w2h, const bfu* __restrict__ w3h,
    bfu* __restrict__ s3h) {

    __shared__ __align__(16) bfu bufA[32768];
    __shared__ __align__(16) bfu w3t[32768];
    __shared__ float xyb[256];
    __shared__ float s1w[128];
    __shared__ float b1s[64], b2s[128], b3s[256];

    bfu* h1t = bufA;            // [n][64]
    bfu* w2t = bufA + 8192;     // [c][64]
    bfu* h2t = bufA + 16384;    // [n][128]

    const int tid = threadIdx.x;
    const int wv = tid >> 6, ln = tid & 63;
    const int e0 = blockIdx.x * 128;

    if (tid < 128) s1w[tid] = Ws1[tid];
    if (tid < 64) b1s[tid] = bs1[tid];
    if (tid < 128) b2s[tid] = bs2[tid];
    b3s[tid] = bs3[tid];

    if (tid < 128) {
        int e = e0 + tid;
        xyb[tid * 2] = el[e * 3]; xyb[tid * 2 + 1] = el[e * 3 + 1];
    }
    for (int i = 0; i < 4; ++i) {
        int cid = i * 256 + tid;
        int row = cid >> 3, c5 = cid & 7;
        short8 v = *(const short8*)(const void*)&w2h[row * 64 + c5 * 8];
        *(short8*)(void*)&w2t[row * 64 + ((c5 ^ (row & 7)) * 8)] = v;
    }
    for (int i = 0; i < 16; ++i) {
        int cid = i * 256 + tid;
        int row = cid >> 4, c5 = cid & 15;
        short8 v = *(const short8*)(const void*)&w3h[row * 128 + c5 * 8];
        *(short8*)(void*)&w3t[row * 128 + ((c5 ^ (row & 7)) * 8)] = v;
    }
    __syncthreads();

    // L1
    {
        int n = tid & 127;
        int j0 = (tid >> 7) * 32;
        float xx = xyb[n * 2], yy = xyb[n * 2 + 1];
        for (int jj = 0; jj < 32; ++jj) {
            int j = j0 + jj;
            float h = sigm(xx * s1w[j] + yy * s1w[64 + j] + b1s[j]);
            h1t[n * 64 + (((j >> 3) ^ (n & 7)) * 8) + (j & 7)] = f2bf(h);
        }
    }
    __syncthreads();

    // L2: (128x64)@(64x128)
    {
        const int mr = (wv >> 1) * 64;
        const int nc = (wv & 1) * 64;
        f32x4 acc[4][4];
        for (int m = 0; m < 4; ++m) for (int nf = 0; nf < 4; ++nf) acc[m][nf] = (f32x4){0.f, 0.f, 0.f, 0.f};
        for (int kk = 0; kk < 2; ++kk) {
            int kc = kk * 4 + (ln >> 4);
            short8 af[4], bf[4];
            for (int m = 0; m < 4; ++m) {
                int row = mr + 16 * m + (ln & 15);
                af[m] = *(const short8*)(const void*)&h1t[row * 64 + ((kc ^ (row & 7)) * 8)];
            }
            for (int nf = 0; nf < 4; ++nf) {
                int c = nc + 16 * nf + (ln & 15);
                bf[nf] = *(const short8*)(const void*)&w2t[c * 64 + ((kc ^ (c & 7)) * 8)];
            }
            for (int m = 0; m < 4; ++m)
                for (int nf = 0; nf < 4; ++nf)
                    acc[m][nf] = __builtin_amdgcn_mfma_f32_16x16x32_bf16(af[m], bf[nf], acc[m][nf], 0, 0, 0);
        }
        for (int m = 0; m < 4; ++m)
            for (int nf = 0; nf < 4; ++nf) {
                int c = nc + 16 * nf + (ln & 15);
                float bb = b2s[c];
                for (int r = 0; r < 4; ++r) {
                    int n = mr + 16 * m + (ln >> 4) * 4 + r;
                    float hh = sigm(acc[m][nf][r] + bb);
                    h2t[n * 128 + (((c >> 3) ^ (n & 7)) * 8) + (c & 7)] = f2bf(hh);
                }
            }
    }
    __syncthreads();

    // L3: (128x128)@(128x256)
    f32x4 acc3[4][8];
    const int mr3 = (wv >> 1) * 64;
    const int nc3 = (wv & 1) * 128;
    for (int m = 0; m < 4; ++m) for (int nf = 0; nf < 8; ++nf) acc3[m][nf] = (f32x4){0.f, 0.f, 0.f, 0.f};
    for (int kk = 0; kk < 4; ++kk) {
        int kc = kk * 4 + (ln >> 4);
        short8 af[4];
        for (int m = 0; m < 4; ++m) {
            int row = mr3 + 16 * m + (ln & 15);
            af[m] = *(const short8*)(const void*)&h2t[row * 128 + ((kc ^ (row & 7)) * 8)];
        }
        for (int nf = 0; nf < 8; ++nf) {
            int c = nc3 + 16 * nf + (ln & 15);
            short8 bf = *(const short8*)(const void*)&w3t[c * 128 + ((kc ^ (c & 7)) * 8)];
            for (int m = 0; m < 4; ++m)
                acc3[m][nf] = __builtin_amdgcn_mfma_f32_16x16x32_bf16(af[m], bf, acc3[m][nf], 0, 0, 0);
        }
    }
    __syncthreads();
    for (int m = 0; m < 4; ++m)
        for (int nf = 0; nf < 8; ++nf) {
            int c = nc3 + 16 * nf + (ln & 15);
            float bb = b3s[c];
            for (int r = 0; r < 4; ++r) {
                int n = mr3 + 16 * m + (ln >> 4) * 4 + r;
                float ss = sigm(acc3[m][nf][r] + bb);
                bufA[n * 256 + (((c >> 3) ^ (n & 7)) * 8) + (c & 7)] = f2bf(ss);
            }
        }
    __syncthreads();
    for (int i = 0; i < 16; ++i) {
        int cid = i * 256 + tid;
        int row = cid >> 5, c5 = cid & 31;
        short8 v = *(const short8*)(const void*)&bufA[row * 256 + ((c5 ^ (row & 7)) * 8)];
        *(short8*)(void*)&s3h[(size_t)(e0 + row) * 256 + c5 * 8] = v;
    }
}

// ---------- phase B: pipelined chunk32, 1 barrier/chunk, no atomics ----------
__global__ __launch_bounds__(512, 1) void k_sipm(
    const float* __restrict__ el, const float* __restrict__ wt,
    const float* __restrict__ bs4, const float* __restrict__ sis,
    const float* __restrict__ Wp1, const float* __restrict__ bp1,
    const float* __restrict__ Wp2, const float* __restrict__ bp2,
    const float* __restrict__ psc,
    const bfu* __restrict__ s3h, const bfu* __restrict__ w4h,
    const int* __restrict__ idxl, const int* __restrict__ counts,
    const int* __restrict__ offs,
    float* __restrict__ outP, float* __restrict__ outS) {

    __shared__ __align__(16) bfu w4t[128 * 256];     // 65536
    __shared__ __align__(16) bfu s3t[2 * 32 * 256];  // 32768 dbuf
    __shared__ __align__(16) bfu rpt[128 * 40];      // 10240 pad-40
    __shared__ __align__(16) bfu Et[2 * 16 * 40];    //  2560 dbuf pad-40
    __shared__ __align__(16) bfu rpp[2 * 16 * 40];   //  2560 dbuf pad-40
    __shared__ float accT[16 * 129];                 //  8256 ring
    __shared__ float accP[64 * 12];                  //  3072
    __shared__ float pwb[444];
    __shared__ float bss[128], si2[128];
    // total 127,792 B

    const int tid = threadIdx.x;
    const int wv = tid >> 6, ln = tid & 63;
    const int bid = blockIdx.x;
    const int st  = bid % NSTILE;
    const int grp = (bid / NSTILE) % NGRP;
    const int b   = bid / (NSTILE * NGRP);
    const int bk0 = grp * GBK;
    const int bk1 = (bk0 + GBK < NBK) ? bk0 + GBK : NBK;
    const int T_lo = bk0 * 8 - 2;
    const int s0 = st * 128;
    const bool do_pmt = (st == 0);
    const int sl = 16 * wv + (ln & 15);

    // ---- init ----
    for (int i = 0; i < 8; ++i) {
        int cid = i * 512 + tid;
        int row = cid >> 5, c5 = cid & 31;
        short8 v = *(const short8*)(const void*)&w4h[(size_t)(s0 + row) * 256 + c5 * 8];
        *(short8*)(void*)&w4t[row * 256 + ((c5 ^ (row & 7)) * 8)] = v;
    }
    if (tid < 128) {
        int s = s0 + tid;
        bss[tid] = (s < NS) ? bs4[s] : 0.0f;
        float sc = (s < NS) ? sis[s] : 0.0f;
        si2[tid] = sc * sc;
    }
    if (do_pmt) {
        if (tid < 444)
            pwb[tid] = (tid < 56) ? Wp1[tid] : (tid < 84) ? bp1[tid - 56] :
                       (tid < 420) ? Wp2[tid - 84] : (tid < 432) ? bp2[tid - 420] : psc[tid - 432];
        if (tid < 256) {   // zero rpp rows 12..15, both buffers
            int bb2 = tid >> 7, p = 12 + ((tid >> 5) & 3), n = tid & 31;
            rpp[bb2 * 640 + p * 40 + n] = 0;
        }
    }
    for (int i = tid; i < 16 * 129; i += 512) accT[i] = 0.f;
    for (int i = tid; i < 64 * 12; i += 512) accP[i] = 0.f;

    // ---- chunk iteration state (block-uniform) ----
    int bk = (bk0 > 0) ? bk0 - 1 : 0;
    int cnt = counts[b * NBK + bk], off = offs[b * NBK + bk];
    int nch = (cnt + 31) >> 5, c = 0;
    while (nch == 0) {
        ++bk;
        if (bk >= bk1) break;
        cnt = counts[b * NBK + bk]; off = offs[b * NBK + bk]; nch = (cnt + 31) >> 5;
    }
    bool have = (bk < bk1);

    // staging registers
    short8 rgA, rgB;
    float zS = 0.f, wS = 0.f, xS = 0.f, yS = 0.f;
    int bkS = 0;

    auto ISSUE = [&](int bkI, int cI, int offI, int cntI) {
        bkS = bkI;
        int liS = cI * 32 + (tid >> 4);
        int gi = offI + liS; gi = gi > 32767 ? 32767 : gi;
        int e = idxl[gi];
        size_t base = (size_t)e * 256;
        rgA = *(const short8*)(const void*)&s3h[base + (tid & 15) * 8];
        rgB = *(const short8*)(const void*)&s3h[base + 128 + (tid & 15) * 8];
        int li2 = cI * 32 + (tid & 31);
        int gi2 = offI + li2; gi2 = gi2 > 32767 ? 32767 : gi2;
        int e2 = idxl[gi2];
        zS = el[e2 * 3 + 2];
        wS = (li2 < cntI) ? wt[e2] : 0.0f;
        if (do_pmt) { xS = el[e2 * 3]; yS = el[e2 * 3 + 1]; }
    };

    auto WSTAGE = [&](int nxt) {
        bfu* s3d = s3t + nxt * 8192;
        int row = tid >> 4, cc = tid & 15;
        *(short8*)(void*)&s3d[row * 256 + ((cc ^ (row & 7)) * 8)] = rgA;
        *(short8*)(void*)&s3d[row * 256 + (((cc + 16) ^ (row & 7)) * 8)] = rgB;
        int j = tid >> 5, n = tid & 31;
        int tg = bkS * 8 - 4 + j;
        int tl = tg - T_lo;
        float d = (float)tg + 0.5f - zS;
        bool ok = (tg >= 0) && (tg < NT) && (tl >= 0) && (tl < 64);
        float g = ok ? wS * GNRM * __expf(-10.0f * d * d) : 0.0f;
        Et[nxt * 640 + j * 40 + n] = f2bf(g);
        if (do_pmt && wv < 6) {
            int p2 = wv * 2 + (ln >> 5);
            float hh[28];
            for (int jj = 0; jj < 28; ++jj)
                hh[jj] = sigm(xS * pwb[jj] + yS * pwb[28 + jj] + pwb[56 + jj]);
            float a = pwb[420 + p2];
            for (int jj = 0; jj < 28; ++jj) a += hh[jj] * pwb[84 + jj * 12 + p2];
            float sc = pwb[432 + p2];
            rpp[nxt * 640 + p2 * 40 + (ln & 31)] = f2bf(sigm(a) * sc * sc);
        }
    };

    if (have) { ISSUE(bk, c, off, cnt); WSTAGE(0); }
    __syncthreads();

    int cur = 0, F = 0;
    while (have) {
        const int cbk = bk, cc0 = c;
        const int db8 = (cbk - bk0) * 8;

        // next chunk coords
        int bkN = bk, cN = c + 1, offN = off, cntN = cnt, nchN = nch;
        if (cN >= nchN) {
            cN = 0;
            for (;;) {
                ++bkN;
                if (bkN >= bk1) { nchN = 0; break; }
                cntN = counts[b * NBK + bkN]; offN = offs[b * NBK + bkN];
                nchN = (cntN + 31) >> 5;
                if (nchN > 0) break;
            }
        }
        bool haveN = (bkN < bk1) && (nchN > 0);

        if (haveN) ISSUE(bkN, cN, offN, cntN);   // loads in flight over GEMM1+GEMM2

        // flush finalized ring rows at bucket entry (uniform branch)
        if (cc0 == 0) {
            int Fn = db8 - 2; Fn = Fn < 0 ? 0 : Fn;
            if (Fn > F) {
                for (int i = tid; i < (Fn - F) * 128; i += 512) {
                    int dr = i >> 7, s = i & 127;
                    int tl = F + dr;
                    float v = accT[(tl & 15) * 129 + s];
                    accT[(tl & 15) * 129 + s] = 0.f;
                    int tg = T_lo + tl, sg = s0 + s;
                    if (tg >= 0 && tg < NT && sg < NS)
                        outS[((size_t)b * NS + sg) * NT + tg] = v;
                }
                F = Fn;
                __syncthreads();                 // ring slots reusable before new adds
            }
        }

        // GEMM1: (32n x 256k) @ (256k x 128s); wave owns 16 s
        const bfu* s3c = s3t + cur * 8192;
        f32x4 acc0 = (f32x4){0.f, 0.f, 0.f, 0.f};
        f32x4 acc1 = (f32x4){0.f, 0.f, 0.f, 0.f};
        const int ar0 = (ln & 15), ar1 = 16 + (ln & 15);
#pragma unroll
        for (int kk = 0; kk < 8; ++kk) {
            int kc = kk * 4 + (ln >> 4);
            short8 bf = *(const short8*)(const void*)&w4t[sl * 256 + ((kc ^ (sl & 7)) * 8)];
            short8 a0 = *(const short8*)(const void*)&s3c[ar0 * 256 + ((kc ^ (ar0 & 7)) * 8)];
            short8 a1 = *(const short8*)(const void*)&s3c[ar1 * 256 + ((kc ^ (ar1 & 7)) * 8)];
            acc0 = __builtin_amdgcn_mfma_f32_16x16x32_bf16(a0, bf, acc0, 0, 0, 0);
            acc1 = __builtin_amdgcn_mfma_f32_16x16x32_bf16(a1, bf, acc1, 0, 0, 0);
        }
        {   // sigmoid*scale^2 -> rpt (wave-local rows)
            float bb = bss[sl], sc = si2[sl];
            short4v pk0, pk1;
            for (int r = 0; r < 4; ++r) pk0[r] = (short)f2bf(sc * sigm(acc0[r] + bb));
            for (int r = 0; r < 4; ++r) pk1[r] = (short)f2bf(sc * sigm(acc1[r] + bb));
            *(short4v*)(void*)&rpt[sl * 40 + (ln >> 4) * 4] = pk0;
            *(short4v*)(void*)&rpt[sl * 40 + 16 + (ln >> 4) * 4] = pk1;
        }

        // GEMM2: Et[cur](16t x 32n) @ rpt -> ring accum
        {
            const bfu* Ec = Et + cur * 640;
            const int tr = ln & 15, kc2 = ln >> 4;
            short8 ea = *(const short8*)(const void*)&Ec[tr * 40 + kc2 * 8];
            short8 bb = *(const short8*)(const void*)&rpt[sl * 40 + kc2 * 8];
            f32x4 a2 = __builtin_amdgcn_mfma_f32_16x16x32_bf16(ea, bb, (f32x4){0.f, 0.f, 0.f, 0.f}, 0, 0, 0);
            for (int r = 0; r < 4; ++r) {
                int tl = db8 - 2 + (ln >> 4) * 4 + r;
                if (tl >= 0 && tl < 64) accT[(tl & 15) * 129 + sl] += a2[r];
            }
            if (do_pmt && wv == 0) {
                const bfu* Rc = rpp + cur * 640;
                short8 bp = *(const short8*)(const void*)&Rc[(ln & 15) * 40 + kc2 * 8];
                f32x4 a2p = __builtin_amdgcn_mfma_f32_16x16x32_bf16(ea, bp, (f32x4){0.f, 0.f, 0.f, 0.f}, 0, 0, 0);
                int p = ln & 15;
                if (p < 12)
                    for (int r = 0; r < 4; ++r) {
                        int tl = db8 - 2 + (ln >> 4) * 4 + r;
                        if (tl >= 0 && tl < 64) accP[tl * 12 + p] += a2p[r];
                    }
            }
        }

        if (haveN) WSTAGE(cur ^ 1);              // vmcnt waits land here
        __syncthreads();                         // the one barrier per chunk
        bk = bkN; c = cN; off = offN; cnt = cntN; nch = nchN; have = haveN; cur ^= 1;
    }

    // final flush [F,64)
    for (int i = tid; i < (64 - F) * 128; i += 512) {
        int dr = i >> 7, s = i & 127;
        int tl = F + dr;
        int tg = T_lo + tl, sg = s0 + s;
        if (tg >= 0 && tg < NT && sg < NS)
            outS[((size_t)b * NS + sg) * NT + tg] = accT[(tl & 15) * 129 + s];
    }
    if (do_pmt) {
        for (int i = tid; i < 64 * 12; i += 512) {
            int tl = i / 12, p = i % 12;
            int tg = T_lo + tl;
            if (tg >= 0 && tg < NT)
                outP[((size_t)b * NP + p) * NT + tg] = accP[tl * 12 + p];
        }
    }
}

extern "C" void kernel_launch(void* const* d_in, const int* in_sizes, int n_in,
                              void* d_out, int out_size, void* d_ws, size_t ws_size,
                              hipStream_t stream) {
    const float* el  = (const float*)d_in[0];
    const float* wt  = (const float*)d_in[1];
    const float* Wp1 = (const float*)d_in[2];
    const float* bp1 = (const float*)d_in[3];
    const float* Wp2 = (const float*)d_in[4];
    const float* bp2 = (const float*)d_in[5];
    const float* psc = (const float*)d_in[6];
    const float* Ws1 = (const float*)d_in[7];
    const float* bs1 = (const float*)d_in[8];
    const float* Ws2 = (const float*)d_in[9];
    const float* bs2 = (const float*)d_in[10];
    const float* Ws3 = (const float*)d_in[11];
    const float* bs3 = (const float*)d_in[12];
    const float* Ws4 = (const float*)d_in[13];
    const float* bs4 = (const float*)d_in[14];
    const float* sis = (const float*)d_in[15];
    float* out = (float*)d_out;

    // workspace layout byte-identical to R2/R4/R5 (proven within ws_size)
    char* ws = (char*)d_ws;
    bfu* w2h     = (bfu*)(ws);                    // 16384
    bfu* w3h     = (bfu*)(ws + 16384);            // 65536
    bfu* w4h     = (bfu*)(ws + 81920);            // 1179648
    bfu* s3h     = (bfu*)(ws + 1261568);          // 16777216
    int* counts  = (int*)(ws + 18038784);
    int* offs    = (int*)(ws + 18042880);
    int* cursors = (int*)(ws + 18046976);
    int* idxl    = (int*)(ws + 18051072);         // 131072 -> end 18182144

    hipMemsetAsync(counts, 0, 4096, stream);
    hipMemsetAsync(cursors, 0, 4096, stream);
    // d_out NOT memset: both outputs are exact-partition plain-stored by k_sipm

    k_prep<<<2464, 256, 0, stream>>>(Ws2, Ws3, Ws4, w2h, w3h, w4h);
    k_count<<<128, 256, 0, stream>>>(el, counts);
    k_scan<<<1, 512, 0, stream>>>(counts, offs);
    k_scatter<<<128, 256, 0, stream>>>(el, offs, cursors, idxl);
    k_mlp<<<256, 256, 0, stream>>>(el, Ws1, bs1, bs2, bs3, w2h, w3h, s3h);
    k_sipm<<<4 * NGRP * NSTILE, 512, 0, stream>>>(el, wt, bs4, sis, Wp1, bp1, Wp2, bp2, psc,
                                                  s3h, w4h, idxl, counts, offs,
                                                  out, out + 4 * NP * NT);
}